// Round 13
// baseline (134.866 us; speedup 1.0000x reference)
//
#include <hip/hip_runtime.h>
#include <hip/hip_bf16.h>

// Problem dims (AdditiveAttention_56865366999388)
#define NB 4
#define NQL 512   // query length
#define ML 512    // key/value length
#define DDIM 256  // DQ == DK == DV
#define HDIM 256  // H

static constexpr float TWO_LOG2E = 2.8853900817779268f; // 2*log2(e)
static constexpr float LOG2E     = 1.4426950408889634f;

// ---------------------------------------------------------------------------
// Kernel 1: projection + exp.  (byte-identical to r11)
// ---------------------------------------------------------------------------
__global__ __launch_bounds__(256) void proj_kernel(
    const float* __restrict__ q_src, const float* __restrict__ k_src,
    const float* __restrict__ Wq,    const float* __restrict__ Wk,
    float* __restrict__ EqT,         float* __restrict__ EkT)
{
    const int z = blockIdx.z;
    const int b = z & 3;
    const int which = z >> 2;
    const float* __restrict__ src  = which ? k_src : q_src;
    const float* __restrict__ W    = which ? Wk    : Wq;
    float* __restrict__       outT = which ? EkT   : EqT;

    const int l0 = blockIdx.x * 32;
    const int h0 = blockIdx.y * 64;
    const int t  = threadIdx.x;
    const int tx = t & 15;   // h group (4 each)
    const int ty = t >> 4;   // l (2 each)

    __shared__ float sX[32][36];   // [dd][ll]  32d x 32l
    __shared__ float sW[32][68];   // [dd][hh]  32d x 64h

    float acc[2][4];
    #pragma unroll
    for (int i = 0; i < 2; i++)
        #pragma unroll
        for (int j = 0; j < 4; j++) acc[i][j] = 0.f;

    const int llA = t >> 3, dgA = t & 7;   // X: 32 l rows x 8 d-groups(4)
    const int ddB = t >> 3, hgB = t & 7;   // W: 32 d rows x 8 h-groups(8)

    for (int d0 = 0; d0 < DDIM; d0 += 32) {
        float4 xv = *(const float4*)&src[(size_t)(b * NQL + l0 + llA) * DDIM + d0 + dgA * 4];
        const float* wrow = &W[(size_t)(d0 + ddB) * HDIM + h0 + hgB * 8];
        float4 wa = ((const float4*)wrow)[0];
        float4 wb = ((const float4*)wrow)[1];
        __syncthreads();
        sX[dgA * 4 + 0][llA] = xv.x;
        sX[dgA * 4 + 1][llA] = xv.y;
        sX[dgA * 4 + 2][llA] = xv.z;
        sX[dgA * 4 + 3][llA] = xv.w;
        *(float4*)&sW[ddB][hgB * 8]     = wa;
        *(float4*)&sW[ddB][hgB * 8 + 4] = wb;
        __syncthreads();
        #pragma unroll
        for (int dd = 0; dd < 32; dd++) {
            float4 w4 = *(const float4*)&sW[dd][tx * 4];
            float2 x2 = *(const float2*)&sX[dd][ty * 2];
            acc[0][0] = fmaf(x2.x, w4.x, acc[0][0]);
            acc[0][1] = fmaf(x2.x, w4.y, acc[0][1]);
            acc[0][2] = fmaf(x2.x, w4.z, acc[0][2]);
            acc[0][3] = fmaf(x2.x, w4.w, acc[0][3]);
            acc[1][0] = fmaf(x2.y, w4.x, acc[1][0]);
            acc[1][1] = fmaf(x2.y, w4.y, acc[1][1]);
            acc[1][2] = fmaf(x2.y, w4.z, acc[1][2]);
            acc[1][3] = fmaf(x2.y, w4.w, acc[1][3]);
        }
    }

    #pragma unroll
    for (int j = 0; j < 4; j++) {
        float2 o;
        o.x = __builtin_amdgcn_exp2f(acc[0][j] * TWO_LOG2E);
        o.y = __builtin_amdgcn_exp2f(acc[1][j] * TWO_LOG2E);
        *(float2*)&outT[(size_t)(b * HDIM + h0 + tx * 4 + j) * NQL + l0 + ty * 2] = o;
    }
}

// ---------------------------------------------------------------------------
// Kernel 2: scores + exp + partial row sums.  (THE ONE CHANGE, resubmitted)
// r9/r10 measured: 42.5us, VALUBusy 57%, conflicts 0 -> LDS-issue-bound.
// Like r11-av's a-operand, q is wave-broadcast (4 distinct 8B addrs/wave,
// 16-lane broadcast) and L1-hot (4KB/chunk footprint, shared by 8 waves/CU):
// read it DIRECTLY from global; sQ + its staging deleted.
// New per-CU-hh bill: LDS 96 cy (k b128 only) < VALU 104 cy/SIMD ->
// VALU-bound at last, occupancy untouched (2 blocks/CU).
// Tile 32n x 64m, 2n x 4m per thread, grid (8,16,4). Math unchanged.
// ---------------------------------------------------------------------------
__global__ __launch_bounds__(256) void scores_kernel(
    const float* __restrict__ EqT, const float* __restrict__ EkT,
    const float* __restrict__ Wv, float* __restrict__ P,
    float* __restrict__ Spart)
{
    const int b  = blockIdx.z;
    const int mt = blockIdx.x;
    const int m0 = mt * 64;
    const int n0 = blockIdx.y * 32;
    const int t  = threadIdx.x;
    const int tx = t & 15;   // m quad (4 each)
    const int ty = t >> 4;   // n pair (2 each)

    __shared__ float sK[32][68];   // [hh][mm] 32h x 64m (+pad)

    float acc0[4] = {}, acc1[4] = {};
    float swv = 0.f;

    const int hhK = t >> 3, ckK = t & 7;  // k staging: 32 h rows x 8 grps(8)

    const float* qcol = &EqT[(size_t)b * HDIM * NQL + n0 + ty * 2];  // this thread's 2 n

    for (int h0 = 0; h0 < HDIM; h0 += 32) {
        const float* krow = &EkT[(size_t)(b * HDIM + h0 + hhK) * ML + m0 + ckK * 8];
        float4 ka = ((const float4*)krow)[0];
        float4 kb = ((const float4*)krow)[1];
        __syncthreads();
        *(float4*)&sK[hhK][ckK * 8]     = ka;
        *(float4*)&sK[hhK][ckK * 8 + 4] = kb;
        __syncthreads();
        #pragma unroll 8
        for (int hh = 0; hh < 32; hh++) {
            float2 q2 = *(const float2*)(qcol + (size_t)(h0 + hh) * NQL);  // global, broadcast
            float4 k4 = *(const float4*)&sK[hh][tx * 4];
            const float wv = Wv[h0 + hh];      // block-uniform -> s_load
            swv += wv;
            const float nw2 = -2.0f * wv;
            {   // n-row 0
                float a0 = fmaf(q2.x, k4.x, 1.0f);   // e^{2(q+k)} + 1
                float a1 = fmaf(q2.x, k4.y, 1.0f);
                float a2 = fmaf(q2.x, k4.z, 1.0f);
                float a3 = fmaf(q2.x, k4.w, 1.0f);
                float r01 = __builtin_amdgcn_rcpf(a0 * a1);
                float r23 = __builtin_amdgcn_rcpf(a2 * a3);
                float t01 = nw2 * r01, t23 = nw2 * r23;
                acc0[0] = fmaf(t01, a1, acc0[0]);
                acc0[1] = fmaf(t01, a0, acc0[1]);
                acc0[2] = fmaf(t23, a3, acc0[2]);
                acc0[3] = fmaf(t23, a2, acc0[3]);
            }
            {   // n-row 1
                float a0 = fmaf(q2.y, k4.x, 1.0f);
                float a1 = fmaf(q2.y, k4.y, 1.0f);
                float a2 = fmaf(q2.y, k4.z, 1.0f);
                float a3 = fmaf(q2.y, k4.w, 1.0f);
                float r01 = __builtin_amdgcn_rcpf(a0 * a1);
                float r23 = __builtin_amdgcn_rcpf(a2 * a3);
                float t01 = nw2 * r01, t23 = nw2 * r23;
                acc1[0] = fmaf(t01, a1, acc1[0]);
                acc1[1] = fmaf(t01, a0, acc1[1]);
                acc1[2] = fmaf(t23, a3, acc1[2]);
                acc1[3] = fmaf(t23, a2, acc1[3]);
            }
        }
    }

    // epilogue: P = exp(S) + per-block partial rowsums (over this block's 64 m)
    float rs0, rs1;
    {
        float4 p;
        p.x = __builtin_amdgcn_exp2f((swv + acc0[0]) * LOG2E);
        p.y = __builtin_amdgcn_exp2f((swv + acc0[1]) * LOG2E);
        p.z = __builtin_amdgcn_exp2f((swv + acc0[2]) * LOG2E);
        p.w = __builtin_amdgcn_exp2f((swv + acc0[3]) * LOG2E);
        *(float4*)&P[(size_t)(b * NQL + n0 + ty * 2 + 0) * ML + m0 + tx * 4] = p;
        rs0 = (p.x + p.y) + (p.z + p.w);
    }
    {
        float4 p;
        p.x = __builtin_amdgcn_exp2f((swv + acc1[0]) * LOG2E);
        p.y = __builtin_amdgcn_exp2f((swv + acc1[1]) * LOG2E);
        p.z = __builtin_amdgcn_exp2f((swv + acc1[2]) * LOG2E);
        p.w = __builtin_amdgcn_exp2f((swv + acc1[3]) * LOG2E);
        *(float4*)&P[(size_t)(b * NQL + n0 + ty * 2 + 1) * ML + m0 + tx * 4] = p;
        rs1 = (p.x + p.y) + (p.z + p.w);
    }
    #pragma unroll
    for (int off = 1; off < 16; off <<= 1) {   // reduce across the 16 tx lanes
        rs0 += __shfl_xor(rs0, off);
        rs1 += __shfl_xor(rs1, off);
    }
    if (tx == 0) {
        Spart[(size_t)(mt * NB + b) * NQL + n0 + ty * 2 + 0] = rs0;
        Spart[(size_t)(mt * NB + b) * NQL + n0 + ty * 2 + 1] = rs1;
    }
}

// ---------------------------------------------------------------------------
// Kernel 3: out[b][n][v] = (sum_m P * V) / rowsum.  (byte-identical to r11)
// ---------------------------------------------------------------------------
__global__ __launch_bounds__(256) void av_kernel(
    const float* __restrict__ P, const float* __restrict__ Spart,
    const float* __restrict__ V, float* __restrict__ O)
{
    const int b  = blockIdx.z;
    const int v0 = blockIdx.x * 64;
    const int n0 = blockIdx.y * 16;
    const int t  = threadIdx.x;
    const int tx = t & 15;   // v group (4 each)
    const int ty = t >> 4;   // n (1 each)

    __shared__ float sV[32][68];  // [mm][vv] 32m x 64v
    __shared__ float sInv[16];

    if (t < 16) {   // softmax denominators from the 8 scores partials
        float s = 0.f;
        #pragma unroll
        for (int mt = 0; mt < 8; ++mt)
            s += Spart[(size_t)(mt * NB + b) * NQL + n0 + t];
        sInv[t] = 1.0f / s;
    }

    float4 acc = {0.f, 0.f, 0.f, 0.f};

    const int mmB = t >> 3, vgB = t & 7;   // V: 32 m rows x 8 v-groups(8)
    const float* prow = &P[(size_t)(b * NQL + n0 + ty) * ML];  // this thread's n-row

    // reg-prefetch V chunk 0
    const float* vrow0 = &V[(size_t)(b * ML + mmB) * DDIM + v0 + vgB * 8];
    float4 va = ((const float4*)vrow0)[0];
    float4 vb = ((const float4*)vrow0)[1];

    for (int m0 = 0; m0 < ML; m0 += 32) {
        __syncthreads();
        *(float4*)&sV[mmB][vgB * 8]     = va;
        *(float4*)&sV[mmB][vgB * 8 + 4] = vb;
        __syncthreads();
        if (m0 + 32 < ML) {   // prefetch next V chunk; hides under compute
            const float* vrow = &V[(size_t)(b * ML + m0 + 32 + mmB) * DDIM + v0 + vgB * 8];
            va = ((const float4*)vrow)[0];
            vb = ((const float4*)vrow)[1];
        }
        #pragma unroll
        for (int mg = 0; mg < 8; ++mg) {
            float4 a4 = *(const float4*)&prow[m0 + mg * 4];   // global, broadcast
            float4 w0 = *(const float4*)&sV[mg * 4 + 0][tx * 4];
            float4 w1 = *(const float4*)&sV[mg * 4 + 1][tx * 4];
            float4 w2 = *(const float4*)&sV[mg * 4 + 2][tx * 4];
            float4 w3 = *(const float4*)&sV[mg * 4 + 3][tx * 4];
            acc.x = fmaf(a4.x, w0.x, acc.x);
            acc.y = fmaf(a4.x, w0.y, acc.y);
            acc.z = fmaf(a4.x, w0.z, acc.z);
            acc.w = fmaf(a4.x, w0.w, acc.w);
            acc.x = fmaf(a4.y, w1.x, acc.x);
            acc.y = fmaf(a4.y, w1.y, acc.y);
            acc.z = fmaf(a4.y, w1.z, acc.z);
            acc.w = fmaf(a4.y, w1.w, acc.w);
            acc.x = fmaf(a4.z, w2.x, acc.x);
            acc.y = fmaf(a4.z, w2.y, acc.y);
            acc.z = fmaf(a4.z, w2.z, acc.z);
            acc.w = fmaf(a4.z, w2.w, acc.w);
            acc.x = fmaf(a4.w, w3.x, acc.x);
            acc.y = fmaf(a4.w, w3.y, acc.y);
            acc.z = fmaf(a4.w, w3.z, acc.z);
            acc.w = fmaf(a4.w, w3.w, acc.w);
        }
    }

    const float inv = sInv[ty];
    float4 o;
    o.x = acc.x * inv;
    o.y = acc.y * inv;
    o.z = acc.z * inv;
    o.w = acc.w * inv;
    *(float4*)&O[(size_t)(b * NQL + n0 + ty) * DDIM + v0 + tx * 4] = o;
}

// ---------------------------------------------------------------------------
extern "C" void kernel_launch(void* const* d_in, const int* in_sizes, int n_in,
                              void* d_out, int out_size, void* d_ws, size_t ws_size,
                              hipStream_t stream)
{
    const float* query = (const float*)d_in[0]; // (4,512,256)
    const float* key   = (const float*)d_in[1]; // (4,512,256)
    const float* value = (const float*)d_in[2]; // (4,512,256)
    const float* Wq    = (const float*)d_in[3]; // (256,256)
    const float* Wk    = (const float*)d_in[4]; // (256,256)
    const float* Wv    = (const float*)d_in[5]; // (256,)
    float* out = (float*)d_out;                 // (4,512,256)

    // workspace layout (fp32): EqT 2MB | EkT 2MB | P 4MB | Spart 64KB
    float* EqT   = (float*)d_ws;                      // [4][256][512]
    float* EkT   = EqT + (size_t)NB * HDIM * NQL;     // [4][256][512]
    float* P     = EkT + (size_t)NB * HDIM * ML;      // [4][512][512] (= exp(S))
    float* Spart = P + (size_t)NB * NQL * ML;         // [8][4][512] partial row sums

    dim3 gProj(NQL / 32, HDIM / 64, NB * 2);
    proj_kernel<<<gProj, 256, 0, stream>>>(query, key, Wq, Wk, EqT, EkT);

    dim3 gSc(ML / 64, NQL / 32, NB);
    scores_kernel<<<gSc, 256, 0, stream>>>(EqT, EkT, Wv, P, Spart);

    dim3 gAv(DDIM / 64, NQL / 16, NB);
    av_kernel<<<gAv, 256, 0, stream>>>(P, Spart, value, out);
}

// Round 14
// 130.778 us; speedup vs baseline: 1.0313x; 1.0313x over previous
//
#include <hip/hip_runtime.h>
#include <hip/hip_bf16.h>

// Problem dims (AdditiveAttention_56865366999388)
#define NB 4
#define NQL 512   // query length
#define ML 512    // key/value length
#define DDIM 256  // DQ == DK == DV
#define HDIM 256  // H

static constexpr float TWO_LOG2E = 2.8853900817779268f; // 2*log2(e)
static constexpr float LOG2E     = 1.4426950408889634f;

// ---------------------------------------------------------------------------
// Kernel 1: projection + exp.  (byte-identical to r11)
// ---------------------------------------------------------------------------
__global__ __launch_bounds__(256) void proj_kernel(
    const float* __restrict__ q_src, const float* __restrict__ k_src,
    const float* __restrict__ Wq,    const float* __restrict__ Wk,
    float* __restrict__ EqT,         float* __restrict__ EkT)
{
    const int z = blockIdx.z;
    const int b = z & 3;
    const int which = z >> 2;
    const float* __restrict__ src  = which ? k_src : q_src;
    const float* __restrict__ W    = which ? Wk    : Wq;
    float* __restrict__       outT = which ? EkT   : EqT;

    const int l0 = blockIdx.x * 32;
    const int h0 = blockIdx.y * 64;
    const int t  = threadIdx.x;
    const int tx = t & 15;   // h group (4 each)
    const int ty = t >> 4;   // l (2 each)

    __shared__ float sX[32][36];   // [dd][ll]  32d x 32l
    __shared__ float sW[32][68];   // [dd][hh]  32d x 64h

    float acc[2][4];
    #pragma unroll
    for (int i = 0; i < 2; i++)
        #pragma unroll
        for (int j = 0; j < 4; j++) acc[i][j] = 0.f;

    const int llA = t >> 3, dgA = t & 7;   // X: 32 l rows x 8 d-groups(4)
    const int ddB = t >> 3, hgB = t & 7;   // W: 32 d rows x 8 h-groups(8)

    for (int d0 = 0; d0 < DDIM; d0 += 32) {
        float4 xv = *(const float4*)&src[(size_t)(b * NQL + l0 + llA) * DDIM + d0 + dgA * 4];
        const float* wrow = &W[(size_t)(d0 + ddB) * HDIM + h0 + hgB * 8];
        float4 wa = ((const float4*)wrow)[0];
        float4 wb = ((const float4*)wrow)[1];
        __syncthreads();
        sX[dgA * 4 + 0][llA] = xv.x;
        sX[dgA * 4 + 1][llA] = xv.y;
        sX[dgA * 4 + 2][llA] = xv.z;
        sX[dgA * 4 + 3][llA] = xv.w;
        *(float4*)&sW[ddB][hgB * 8]     = wa;
        *(float4*)&sW[ddB][hgB * 8 + 4] = wb;
        __syncthreads();
        #pragma unroll
        for (int dd = 0; dd < 32; dd++) {
            float4 w4 = *(const float4*)&sW[dd][tx * 4];
            float2 x2 = *(const float2*)&sX[dd][ty * 2];
            acc[0][0] = fmaf(x2.x, w4.x, acc[0][0]);
            acc[0][1] = fmaf(x2.x, w4.y, acc[0][1]);
            acc[0][2] = fmaf(x2.x, w4.z, acc[0][2]);
            acc[0][3] = fmaf(x2.x, w4.w, acc[0][3]);
            acc[1][0] = fmaf(x2.y, w4.x, acc[1][0]);
            acc[1][1] = fmaf(x2.y, w4.y, acc[1][1]);
            acc[1][2] = fmaf(x2.y, w4.z, acc[1][2]);
            acc[1][3] = fmaf(x2.y, w4.w, acc[1][3]);
        }
    }

    #pragma unroll
    for (int j = 0; j < 4; j++) {
        float2 o;
        o.x = __builtin_amdgcn_exp2f(acc[0][j] * TWO_LOG2E);
        o.y = __builtin_amdgcn_exp2f(acc[1][j] * TWO_LOG2E);
        *(float2*)&outT[(size_t)(b * HDIM + h0 + tx * 4 + j) * NQL + l0 + ty * 2] = o;
    }
}

// ---------------------------------------------------------------------------
// Kernel 2: scores + exp + partial row sums.  (THE ONE CHANGE vs r11)
// Four structurally different variants all measured/inferred ~42us ->
// delivery- and occupancy-insensitive. Last untested element: barrier
// rhythm. r11 used 2 barriers/chunk with k-load latency exposed per chunk.
// Now: LDS double-buffer (sQ[2], sK[2], 26.6KB), ONE barrier per chunk:
//   { write buf[cur]; barrier; prefetch c+1 regs; compute buf[cur]; flip }
// Correctness: barrier at chunk c guarantees all threads finished chunk
// c-1's compute (it precedes their write of c), so writing buf[cur^1] at
// c+1 never races readers. Next-chunk global loads stay in flight across
// the whole compute phase (~1300cy >> ~400cy latency).
// Tile 32n x 64m, 2n x 4m/thread, grid (8,16,4) = 512 blocks. Math as r11.
// ---------------------------------------------------------------------------
__global__ __launch_bounds__(256) void scores_kernel(
    const float* __restrict__ EqT, const float* __restrict__ EkT,
    const float* __restrict__ Wv, float* __restrict__ P,
    float* __restrict__ Spart)
{
    const int b  = blockIdx.z;
    const int mt = blockIdx.x;
    const int m0 = mt * 64;
    const int n0 = blockIdx.y * 32;
    const int t  = threadIdx.x;
    const int tx = t & 15;   // m quad (4 each)
    const int ty = t >> 4;   // n pair (2 each)

    __shared__ float sQ[2][32][36];   // [buf][hh][nn] 32h x 32n (+pad)
    __shared__ float sK[2][32][68];   // [buf][hh][mm] 32h x 64m (+pad)

    float acc0[4] = {}, acc1[4] = {};
    float swv = 0.f;

    const int hhA = t >> 3, cgA = t & 7;  // q staging: 32 h rows x 8 grps(4)
    const int hhK = t >> 3, ckK = t & 7;  // k staging: 32 h rows x 8 grps(8)

    const float* qbase = &EqT[(size_t)b * HDIM * NQL + n0];
    const float* kbase = &EkT[(size_t)b * HDIM * ML + m0];

    // preload chunk 0 into staging regs
    float4 qv = *(const float4*)(qbase + (size_t)hhA * NQL + cgA * 4);
    const float* kr0 = kbase + (size_t)hhK * ML + ckK * 8;
    float4 ka = ((const float4*)kr0)[0];
    float4 kb = ((const float4*)kr0)[1];

    int cur = 0;
    for (int c = 0; c < 8; ++c) {   // 8 chunks of 32 hh
        *(float4*)&sQ[cur][hhA][cgA * 4]     = qv;
        *(float4*)&sK[cur][hhK][ckK * 8]     = ka;
        *(float4*)&sK[cur][hhK][ckK * 8 + 4] = kb;
        __syncthreads();
        if (c < 7) {   // next-chunk loads: in flight across this compute phase
            const float* qn = qbase + (size_t)((c + 1) * 32 + hhA) * NQL;
            qv = *(const float4*)(qn + cgA * 4);
            const float* kn = kbase + (size_t)((c + 1) * 32 + hhK) * ML + ckK * 8;
            ka = ((const float4*)kn)[0];
            kb = ((const float4*)kn)[1];
        }
        const int h0 = c * 32;
        #pragma unroll 8
        for (int hh = 0; hh < 32; hh++) {
            float2 q2 = *(const float2*)&sQ[cur][hh][ty * 2];
            float4 k4 = *(const float4*)&sK[cur][hh][tx * 4];
            const float wv = Wv[h0 + hh];      // block-uniform -> s_load
            swv += wv;
            const float nw2 = -2.0f * wv;
            {   // n-row 0
                float a0 = fmaf(q2.x, k4.x, 1.0f);   // e^{2(q+k)} + 1
                float a1 = fmaf(q2.x, k4.y, 1.0f);
                float a2 = fmaf(q2.x, k4.z, 1.0f);
                float a3 = fmaf(q2.x, k4.w, 1.0f);
                float r01 = __builtin_amdgcn_rcpf(a0 * a1);
                float r23 = __builtin_amdgcn_rcpf(a2 * a3);
                float t01 = nw2 * r01, t23 = nw2 * r23;
                acc0[0] = fmaf(t01, a1, acc0[0]);
                acc0[1] = fmaf(t01, a0, acc0[1]);
                acc0[2] = fmaf(t23, a3, acc0[2]);
                acc0[3] = fmaf(t23, a2, acc0[3]);
            }
            {   // n-row 1
                float a0 = fmaf(q2.y, k4.x, 1.0f);
                float a1 = fmaf(q2.y, k4.y, 1.0f);
                float a2 = fmaf(q2.y, k4.z, 1.0f);
                float a3 = fmaf(q2.y, k4.w, 1.0f);
                float r01 = __builtin_amdgcn_rcpf(a0 * a1);
                float r23 = __builtin_amdgcn_rcpf(a2 * a3);
                float t01 = nw2 * r01, t23 = nw2 * r23;
                acc1[0] = fmaf(t01, a1, acc1[0]);
                acc1[1] = fmaf(t01, a0, acc1[1]);
                acc1[2] = fmaf(t23, a3, acc1[2]);
                acc1[3] = fmaf(t23, a2, acc1[3]);
            }
        }
        cur ^= 1;
    }

    // epilogue: P = exp(S) + per-block partial rowsums (over this block's 64 m)
    float rs0, rs1;
    {
        float4 p;
        p.x = __builtin_amdgcn_exp2f((swv + acc0[0]) * LOG2E);
        p.y = __builtin_amdgcn_exp2f((swv + acc0[1]) * LOG2E);
        p.z = __builtin_amdgcn_exp2f((swv + acc0[2]) * LOG2E);
        p.w = __builtin_amdgcn_exp2f((swv + acc0[3]) * LOG2E);
        *(float4*)&P[(size_t)(b * NQL + n0 + ty * 2 + 0) * ML + m0 + tx * 4] = p;
        rs0 = (p.x + p.y) + (p.z + p.w);
    }
    {
        float4 p;
        p.x = __builtin_amdgcn_exp2f((swv + acc1[0]) * LOG2E);
        p.y = __builtin_amdgcn_exp2f((swv + acc1[1]) * LOG2E);
        p.z = __builtin_amdgcn_exp2f((swv + acc1[2]) * LOG2E);
        p.w = __builtin_amdgcn_exp2f((swv + acc1[3]) * LOG2E);
        *(float4*)&P[(size_t)(b * NQL + n0 + ty * 2 + 1) * ML + m0 + tx * 4] = p;
        rs1 = (p.x + p.y) + (p.z + p.w);
    }
    #pragma unroll
    for (int off = 1; off < 16; off <<= 1) {   // reduce across the 16 tx lanes
        rs0 += __shfl_xor(rs0, off);
        rs1 += __shfl_xor(rs1, off);
    }
    if (tx == 0) {
        Spart[(size_t)(mt * NB + b) * NQL + n0 + ty * 2 + 0] = rs0;
        Spart[(size_t)(mt * NB + b) * NQL + n0 + ty * 2 + 1] = rs1;
    }
}

// ---------------------------------------------------------------------------
// Kernel 3: out[b][n][v] = (sum_m P * V) / rowsum.  (byte-identical to r11)
// ---------------------------------------------------------------------------
__global__ __launch_bounds__(256) void av_kernel(
    const float* __restrict__ P, const float* __restrict__ Spart,
    const float* __restrict__ V, float* __restrict__ O)
{
    const int b  = blockIdx.z;
    const int v0 = blockIdx.x * 64;
    const int n0 = blockIdx.y * 16;
    const int t  = threadIdx.x;
    const int tx = t & 15;   // v group (4 each)
    const int ty = t >> 4;   // n (1 each)

    __shared__ float sV[32][68];  // [mm][vv] 32m x 64v
    __shared__ float sInv[16];

    if (t < 16) {   // softmax denominators from the 8 scores partials
        float s = 0.f;
        #pragma unroll
        for (int mt = 0; mt < 8; ++mt)
            s += Spart[(size_t)(mt * NB + b) * NQL + n0 + t];
        sInv[t] = 1.0f / s;
    }

    float4 acc = {0.f, 0.f, 0.f, 0.f};

    const int mmB = t >> 3, vgB = t & 7;   // V: 32 m rows x 8 v-groups(8)
    const float* prow = &P[(size_t)(b * NQL + n0 + ty) * ML];  // this thread's n-row

    // reg-prefetch V chunk 0
    const float* vrow0 = &V[(size_t)(b * ML + mmB) * DDIM + v0 + vgB * 8];
    float4 va = ((const float4*)vrow0)[0];
    float4 vb = ((const float4*)vrow0)[1];

    for (int m0 = 0; m0 < ML; m0 += 32) {
        __syncthreads();
        *(float4*)&sV[mmB][vgB * 8]     = va;
        *(float4*)&sV[mmB][vgB * 8 + 4] = vb;
        __syncthreads();
        if (m0 + 32 < ML) {   // prefetch next V chunk; hides under compute
            const float* vrow = &V[(size_t)(b * ML + m0 + 32 + mmB) * DDIM + v0 + vgB * 8];
            va = ((const float4*)vrow)[0];
            vb = ((const float4*)vrow)[1];
        }
        #pragma unroll
        for (int mg = 0; mg < 8; ++mg) {
            float4 a4 = *(const float4*)&prow[m0 + mg * 4];   // global, broadcast
            float4 w0 = *(const float4*)&sV[mg * 4 + 0][tx * 4];
            float4 w1 = *(const float4*)&sV[mg * 4 + 1][tx * 4];
            float4 w2 = *(const float4*)&sV[mg * 4 + 2][tx * 4];
            float4 w3 = *(const float4*)&sV[mg * 4 + 3][tx * 4];
            acc.x = fmaf(a4.x, w0.x, acc.x);
            acc.y = fmaf(a4.x, w0.y, acc.y);
            acc.z = fmaf(a4.x, w0.z, acc.z);
            acc.w = fmaf(a4.x, w0.w, acc.w);
            acc.x = fmaf(a4.y, w1.x, acc.x);
            acc.y = fmaf(a4.y, w1.y, acc.y);
            acc.z = fmaf(a4.y, w1.z, acc.z);
            acc.w = fmaf(a4.y, w1.w, acc.w);
            acc.x = fmaf(a4.z, w2.x, acc.x);
            acc.y = fmaf(a4.z, w2.y, acc.y);
            acc.z = fmaf(a4.z, w2.z, acc.z);
            acc.w = fmaf(a4.z, w2.w, acc.w);
            acc.x = fmaf(a4.w, w3.x, acc.x);
            acc.y = fmaf(a4.w, w3.y, acc.y);
            acc.z = fmaf(a4.w, w3.z, acc.z);
            acc.w = fmaf(a4.w, w3.w, acc.w);
        }
    }

    const float inv = sInv[ty];
    float4 o;
    o.x = acc.x * inv;
    o.y = acc.y * inv;
    o.z = acc.z * inv;
    o.w = acc.w * inv;
    *(float4*)&O[(size_t)(b * NQL + n0 + ty) * DDIM + v0 + tx * 4] = o;
}

// ---------------------------------------------------------------------------
extern "C" void kernel_launch(void* const* d_in, const int* in_sizes, int n_in,
                              void* d_out, int out_size, void* d_ws, size_t ws_size,
                              hipStream_t stream)
{
    const float* query = (const float*)d_in[0]; // (4,512,256)
    const float* key   = (const float*)d_in[1]; // (4,512,256)
    const float* value = (const float*)d_in[2]; // (4,512,256)
    const float* Wq    = (const float*)d_in[3]; // (256,256)
    const float* Wk    = (const float*)d_in[4]; // (256,256)
    const float* Wv    = (const float*)d_in[5]; // (256,)
    float* out = (float*)d_out;                 // (4,512,256)

    // workspace layout (fp32): EqT 2MB | EkT 2MB | P 4MB | Spart 64KB
    float* EqT   = (float*)d_ws;                      // [4][256][512]
    float* EkT   = EqT + (size_t)NB * HDIM * NQL;     // [4][256][512]
    float* P     = EkT + (size_t)NB * HDIM * ML;      // [4][512][512] (= exp(S))
    float* Spart = P + (size_t)NB * NQL * ML;         // [8][4][512] partial row sums

    dim3 gProj(NQL / 32, HDIM / 64, NB * 2);
    proj_kernel<<<gProj, 256, 0, stream>>>(query, key, Wq, Wk, EqT, EkT);

    dim3 gSc(ML / 64, NQL / 32, NB);
    scores_kernel<<<gSc, 256, 0, stream>>>(EqT, EkT, Wv, P, Spart);

    dim3 gAv(DDIM / 64, NQL / 16, NB);
    av_kernel<<<gAv, 256, 0, stream>>>(P, Spart, value, out);
}

// Round 15
// 129.479 us; speedup vs baseline: 1.0416x; 1.0100x over previous
//
#include <hip/hip_runtime.h>
#include <hip/hip_bf16.h>

// Problem dims (AdditiveAttention_56865366999388)
#define NB 4
#define NQL 512   // query length
#define ML 512    // key/value length
#define DDIM 256  // DQ == DK == DV
#define HDIM 256  // H

static constexpr float TWO_LOG2E = 2.8853900817779268f; // 2*log2(e)
static constexpr float LOG2E     = 1.4426950408889634f;

// ---------------------------------------------------------------------------
// Kernel 1: projection + exp.  (r11 kernel + the r14-validated single-barrier
// LDS double-buffer: {write buf[cur]; barrier; prefetch c+1; compute; flip})
// 32l x 64h tile, 2l x 4h per thread, grid (16,4,8). LDS 26.6 KB.
// ---------------------------------------------------------------------------
__global__ __launch_bounds__(256) void proj_kernel(
    const float* __restrict__ q_src, const float* __restrict__ k_src,
    const float* __restrict__ Wq,    const float* __restrict__ Wk,
    float* __restrict__ EqT,         float* __restrict__ EkT)
{
    const int z = blockIdx.z;
    const int b = z & 3;
    const int which = z >> 2;
    const float* __restrict__ src  = which ? k_src : q_src;
    const float* __restrict__ W    = which ? Wk    : Wq;
    float* __restrict__       outT = which ? EkT   : EqT;

    const int l0 = blockIdx.x * 32;
    const int h0 = blockIdx.y * 64;
    const int t  = threadIdx.x;
    const int tx = t & 15;   // h group (4 each)
    const int ty = t >> 4;   // l (2 each)

    __shared__ float sX[2][32][36];   // [buf][dd][ll]  32d x 32l
    __shared__ float sW[2][32][68];   // [buf][dd][hh]  32d x 64h

    float acc[2][4];
    #pragma unroll
    for (int i = 0; i < 2; i++)
        #pragma unroll
        for (int j = 0; j < 4; j++) acc[i][j] = 0.f;

    const int llA = t >> 3, dgA = t & 7;   // X: 32 l rows x 8 d-groups(4)
    const int ddB = t >> 3, hgB = t & 7;   // W: 32 d rows x 8 h-groups(8)

    // preload chunk 0
    float4 xv = *(const float4*)&src[(size_t)(b * NQL + l0 + llA) * DDIM + dgA * 4];
    const float* wr0 = &W[(size_t)ddB * HDIM + h0 + hgB * 8];
    float4 wa = ((const float4*)wr0)[0];
    float4 wb = ((const float4*)wr0)[1];

    int cur = 0;
    for (int c = 0; c < 8; ++c) {   // 8 chunks of 32 d
        sX[cur][dgA * 4 + 0][llA] = xv.x;
        sX[cur][dgA * 4 + 1][llA] = xv.y;
        sX[cur][dgA * 4 + 2][llA] = xv.z;
        sX[cur][dgA * 4 + 3][llA] = xv.w;
        *(float4*)&sW[cur][ddB][hgB * 8]     = wa;
        *(float4*)&sW[cur][ddB][hgB * 8 + 4] = wb;
        __syncthreads();
        if (c < 7) {   // next-chunk loads stay in flight across this compute
            const int d0 = (c + 1) * 32;
            xv = *(const float4*)&src[(size_t)(b * NQL + l0 + llA) * DDIM + d0 + dgA * 4];
            const float* wrow = &W[(size_t)(d0 + ddB) * HDIM + h0 + hgB * 8];
            wa = ((const float4*)wrow)[0];
            wb = ((const float4*)wrow)[1];
        }
        #pragma unroll
        for (int dd = 0; dd < 32; dd++) {
            float4 w4 = *(const float4*)&sW[cur][dd][tx * 4];
            float2 x2 = *(const float2*)&sX[cur][dd][ty * 2];
            acc[0][0] = fmaf(x2.x, w4.x, acc[0][0]);
            acc[0][1] = fmaf(x2.x, w4.y, acc[0][1]);
            acc[0][2] = fmaf(x2.x, w4.z, acc[0][2]);
            acc[0][3] = fmaf(x2.x, w4.w, acc[0][3]);
            acc[1][0] = fmaf(x2.y, w4.x, acc[1][0]);
            acc[1][1] = fmaf(x2.y, w4.y, acc[1][1]);
            acc[1][2] = fmaf(x2.y, w4.z, acc[1][2]);
            acc[1][3] = fmaf(x2.y, w4.w, acc[1][3]);
        }
        cur ^= 1;
    }

    #pragma unroll
    for (int j = 0; j < 4; j++) {
        float2 o;
        o.x = __builtin_amdgcn_exp2f(acc[0][j] * TWO_LOG2E);
        o.y = __builtin_amdgcn_exp2f(acc[1][j] * TWO_LOG2E);
        *(float2*)&outT[(size_t)(b * HDIM + h0 + tx * 4 + j) * NQL + l0 + ty * 2] = o;
    }
}

// ---------------------------------------------------------------------------
// Kernel 2: scores + exp + partial row sums.  (byte-identical to r14)
// ---------------------------------------------------------------------------
__global__ __launch_bounds__(256) void scores_kernel(
    const float* __restrict__ EqT, const float* __restrict__ EkT,
    const float* __restrict__ Wv, float* __restrict__ P,
    float* __restrict__ Spart)
{
    const int b  = blockIdx.z;
    const int mt = blockIdx.x;
    const int m0 = mt * 64;
    const int n0 = blockIdx.y * 32;
    const int t  = threadIdx.x;
    const int tx = t & 15;   // m quad (4 each)
    const int ty = t >> 4;   // n pair (2 each)

    __shared__ float sQ[2][32][36];   // [buf][hh][nn] 32h x 32n (+pad)
    __shared__ float sK[2][32][68];   // [buf][hh][mm] 32h x 64m (+pad)

    float acc0[4] = {}, acc1[4] = {};
    float swv = 0.f;

    const int hhA = t >> 3, cgA = t & 7;  // q staging: 32 h rows x 8 grps(4)
    const int hhK = t >> 3, ckK = t & 7;  // k staging: 32 h rows x 8 grps(8)

    const float* qbase = &EqT[(size_t)b * HDIM * NQL + n0];
    const float* kbase = &EkT[(size_t)b * HDIM * ML + m0];

    // preload chunk 0 into staging regs
    float4 qv = *(const float4*)(qbase + (size_t)hhA * NQL + cgA * 4);
    const float* kr0 = kbase + (size_t)hhK * ML + ckK * 8;
    float4 ka = ((const float4*)kr0)[0];
    float4 kb = ((const float4*)kr0)[1];

    int cur = 0;
    for (int c = 0; c < 8; ++c) {   // 8 chunks of 32 hh
        *(float4*)&sQ[cur][hhA][cgA * 4]     = qv;
        *(float4*)&sK[cur][hhK][ckK * 8]     = ka;
        *(float4*)&sK[cur][hhK][ckK * 8 + 4] = kb;
        __syncthreads();
        if (c < 7) {   // next-chunk loads: in flight across this compute phase
            const float* qn = qbase + (size_t)((c + 1) * 32 + hhA) * NQL;
            qv = *(const float4*)(qn + cgA * 4);
            const float* kn = kbase + (size_t)((c + 1) * 32 + hhK) * ML + ckK * 8;
            ka = ((const float4*)kn)[0];
            kb = ((const float4*)kn)[1];
        }
        const int h0 = c * 32;
        #pragma unroll 8
        for (int hh = 0; hh < 32; hh++) {
            float2 q2 = *(const float2*)&sQ[cur][hh][ty * 2];
            float4 k4 = *(const float4*)&sK[cur][hh][tx * 4];
            const float wv = Wv[h0 + hh];      // block-uniform -> s_load
            swv += wv;
            const float nw2 = -2.0f * wv;
            {   // n-row 0
                float a0 = fmaf(q2.x, k4.x, 1.0f);   // e^{2(q+k)} + 1
                float a1 = fmaf(q2.x, k4.y, 1.0f);
                float a2 = fmaf(q2.x, k4.z, 1.0f);
                float a3 = fmaf(q2.x, k4.w, 1.0f);
                float r01 = __builtin_amdgcn_rcpf(a0 * a1);
                float r23 = __builtin_amdgcn_rcpf(a2 * a3);
                float t01 = nw2 * r01, t23 = nw2 * r23;
                acc0[0] = fmaf(t01, a1, acc0[0]);
                acc0[1] = fmaf(t01, a0, acc0[1]);
                acc0[2] = fmaf(t23, a3, acc0[2]);
                acc0[3] = fmaf(t23, a2, acc0[3]);
            }
            {   // n-row 1
                float a0 = fmaf(q2.y, k4.x, 1.0f);
                float a1 = fmaf(q2.y, k4.y, 1.0f);
                float a2 = fmaf(q2.y, k4.z, 1.0f);
                float a3 = fmaf(q2.y, k4.w, 1.0f);
                float r01 = __builtin_amdgcn_rcpf(a0 * a1);
                float r23 = __builtin_amdgcn_rcpf(a2 * a3);
                float t01 = nw2 * r01, t23 = nw2 * r23;
                acc1[0] = fmaf(t01, a1, acc1[0]);
                acc1[1] = fmaf(t01, a0, acc1[1]);
                acc1[2] = fmaf(t23, a3, acc1[2]);
                acc1[3] = fmaf(t23, a2, acc1[3]);
            }
        }
        cur ^= 1;
    }

    // epilogue: P = exp(S) + per-block partial rowsums (over this block's 64 m)
    float rs0, rs1;
    {
        float4 p;
        p.x = __builtin_amdgcn_exp2f((swv + acc0[0]) * LOG2E);
        p.y = __builtin_amdgcn_exp2f((swv + acc0[1]) * LOG2E);
        p.z = __builtin_amdgcn_exp2f((swv + acc0[2]) * LOG2E);
        p.w = __builtin_amdgcn_exp2f((swv + acc0[3]) * LOG2E);
        *(float4*)&P[(size_t)(b * NQL + n0 + ty * 2 + 0) * ML + m0 + tx * 4] = p;
        rs0 = (p.x + p.y) + (p.z + p.w);
    }
    {
        float4 p;
        p.x = __builtin_amdgcn_exp2f((swv + acc1[0]) * LOG2E);
        p.y = __builtin_amdgcn_exp2f((swv + acc1[1]) * LOG2E);
        p.z = __builtin_amdgcn_exp2f((swv + acc1[2]) * LOG2E);
        p.w = __builtin_amdgcn_exp2f((swv + acc1[3]) * LOG2E);
        *(float4*)&P[(size_t)(b * NQL + n0 + ty * 2 + 1) * ML + m0 + tx * 4] = p;
        rs1 = (p.x + p.y) + (p.z + p.w);
    }
    #pragma unroll
    for (int off = 1; off < 16; off <<= 1) {   // reduce across the 16 tx lanes
        rs0 += __shfl_xor(rs0, off);
        rs1 += __shfl_xor(rs1, off);
    }
    if (tx == 0) {
        Spart[(size_t)(mt * NB + b) * NQL + n0 + ty * 2 + 0] = rs0;
        Spart[(size_t)(mt * NB + b) * NQL + n0 + ty * 2 + 1] = rs1;
    }
}

// ---------------------------------------------------------------------------
// Kernel 3: out[b][n][v] = (sum_m P * V) / rowsum.  (r11 kernel + the same
// single-barrier V double-buffer; a4 stays direct-global. LDS 17.4 KB.)
// grid: (4, 32, 4) = 512 blocks. block 256. 16n x 64v tile, 1n x 4v/thread.
// ---------------------------------------------------------------------------
__global__ __launch_bounds__(256) void av_kernel(
    const float* __restrict__ P, const float* __restrict__ Spart,
    const float* __restrict__ V, float* __restrict__ O)
{
    const int b  = blockIdx.z;
    const int v0 = blockIdx.x * 64;
    const int n0 = blockIdx.y * 16;
    const int t  = threadIdx.x;
    const int tx = t & 15;   // v group (4 each)
    const int ty = t >> 4;   // n (1 each)

    __shared__ float sV[2][32][68];  // [buf][mm][vv] 32m x 64v
    __shared__ float sInv[16];

    if (t < 16) {   // softmax denominators from the 8 scores partials
        float s = 0.f;
        #pragma unroll
        for (int mt = 0; mt < 8; ++mt)
            s += Spart[(size_t)(mt * NB + b) * NQL + n0 + t];
        sInv[t] = 1.0f / s;
    }

    float4 acc = {0.f, 0.f, 0.f, 0.f};

    const int mmB = t >> 3, vgB = t & 7;   // V: 32 m rows x 8 v-groups(8)
    const float* prow = &P[(size_t)(b * NQL + n0 + ty) * ML];  // this thread's n-row

    // preload V chunk 0
    const float* vrow0 = &V[(size_t)(b * ML + mmB) * DDIM + v0 + vgB * 8];
    float4 va = ((const float4*)vrow0)[0];
    float4 vb = ((const float4*)vrow0)[1];

    int cur = 0;
    for (int m0 = 0; m0 < ML; m0 += 32) {
        *(float4*)&sV[cur][mmB][vgB * 8]     = va;
        *(float4*)&sV[cur][mmB][vgB * 8 + 4] = vb;
        __syncthreads();
        if (m0 + 32 < ML) {   // next V chunk in flight across this compute
            const float* vrow = &V[(size_t)(b * ML + m0 + 32 + mmB) * DDIM + v0 + vgB * 8];
            va = ((const float4*)vrow)[0];
            vb = ((const float4*)vrow)[1];
        }
        #pragma unroll
        for (int mg = 0; mg < 8; ++mg) {
            float4 a4 = *(const float4*)&prow[m0 + mg * 4];   // global, broadcast
            float4 w0 = *(const float4*)&sV[cur][mg * 4 + 0][tx * 4];
            float4 w1 = *(const float4*)&sV[cur][mg * 4 + 1][tx * 4];
            float4 w2 = *(const float4*)&sV[cur][mg * 4 + 2][tx * 4];
            float4 w3 = *(const float4*)&sV[cur][mg * 4 + 3][tx * 4];
            acc.x = fmaf(a4.x, w0.x, acc.x);
            acc.y = fmaf(a4.x, w0.y, acc.y);
            acc.z = fmaf(a4.x, w0.z, acc.z);
            acc.w = fmaf(a4.x, w0.w, acc.w);
            acc.x = fmaf(a4.y, w1.x, acc.x);
            acc.y = fmaf(a4.y, w1.y, acc.y);
            acc.z = fmaf(a4.y, w1.z, acc.z);
            acc.w = fmaf(a4.y, w1.w, acc.w);
            acc.x = fmaf(a4.z, w2.x, acc.x);
            acc.y = fmaf(a4.z, w2.y, acc.y);
            acc.z = fmaf(a4.z, w2.z, acc.z);
            acc.w = fmaf(a4.z, w2.w, acc.w);
            acc.x = fmaf(a4.w, w3.x, acc.x);
            acc.y = fmaf(a4.w, w3.y, acc.y);
            acc.z = fmaf(a4.w, w3.z, acc.z);
            acc.w = fmaf(a4.w, w3.w, acc.w);
        }
        cur ^= 1;
    }

    const float inv = sInv[ty];
    float4 o;
    o.x = acc.x * inv;
    o.y = acc.y * inv;
    o.z = acc.z * inv;
    o.w = acc.w * inv;
    *(float4*)&O[(size_t)(b * NQL + n0 + ty) * DDIM + v0 + tx * 4] = o;
}

// ---------------------------------------------------------------------------
extern "C" void kernel_launch(void* const* d_in, const int* in_sizes, int n_in,
                              void* d_out, int out_size, void* d_ws, size_t ws_size,
                              hipStream_t stream)
{
    const float* query = (const float*)d_in[0]; // (4,512,256)
    const float* key   = (const float*)d_in[1]; // (4,512,256)
    const float* value = (const float*)d_in[2]; // (4,512,256)
    const float* Wq    = (const float*)d_in[3]; // (256,256)
    const float* Wk    = (const float*)d_in[4]; // (256,256)
    const float* Wv    = (const float*)d_in[5]; // (256,)
    float* out = (float*)d_out;                 // (4,512,256)

    // workspace layout (fp32): EqT 2MB | EkT 2MB | P 4MB | Spart 64KB
    float* EqT   = (float*)d_ws;                      // [4][256][512]
    float* EkT   = EqT + (size_t)NB * HDIM * NQL;     // [4][256][512]
    float* P     = EkT + (size_t)NB * HDIM * ML;      // [4][512][512] (= exp(S))
    float* Spart = P + (size_t)NB * NQL * ML;         // [8][4][512] partial row sums

    dim3 gProj(NQL / 32, HDIM / 64, NB * 2);
    proj_kernel<<<gProj, 256, 0, stream>>>(query, key, Wq, Wk, EqT, EkT);

    dim3 gSc(ML / 64, NQL / 32, NB);
    scores_kernel<<<gSc, 256, 0, stream>>>(EqT, EkT, Wv, P, Spart);

    dim3 gAv(DDIM / 64, NQL / 16, NB);
    av_kernel<<<gAv, 256, 0, stream>>>(P, Spart, value, out);
}